// Round 4
// baseline (196.866 us; speedup 1.0000x reference)
//
#include <hip/hip_runtime.h>
#include <cstdint>

// Problem constants (from reference)
constexpr int B_   = 4096;
constexpr int T_   = 512;
constexpr int DIN  = 10;
constexpr int H_   = 20;
constexpr int DOUT = 2;

constexpr int SPW = 3;            // samples per block (3 x 20 = 60 active lanes/wave)
constexpr int CH  = 4;            // timesteps of x per chunk (wave0)
constexpr int XV  = CH * DIN / 4; // 10 float4 per chunk

// Compiler-only fence (no instructions): pins LDS op ordering.
#define CFENCE() asm volatile("" ::: "memory")
// Retire outstanding DS ops (used after the handoff ds_write, before barrier).
#define LGKM0()  asm volatile("s_waitcnt lgkmcnt(0)" ::: "memory")
// Raw barrier: NO vmcnt drain (unlike __syncthreads) -> x prefetch stays in flight.
#define BAR()    do { CFENCE(); __builtin_amdgcn_s_barrier(); CFENCE(); } while (0)

__device__ __forceinline__ float fast_tanh(float v) {
    // tanh(v) = 1 - 2/(exp2(2*log2e*v)+1): 5 VALU ops, exact saturation
    float e = __builtin_amdgcn_exp2f(v * 2.885390082f);
    float r = __builtin_amdgcn_rcpf(e + 1.0f);
    return fmaf(-2.0f, r, 1.0f);
}

// Two waves per block: wave0 = layer-0 producer, wave1 = layer-1 consumer,
// software-pipelined with skew 1 step; h1 handed off via double-buffered LDS.
extern "C" __global__ void __launch_bounds__(128, 2)
rnn_pipe(const float* __restrict__ x,
         const float* __restrict__ w_ih0, const float* __restrict__ w_hh0,
         const float* __restrict__ b_ih0, const float* __restrict__ b_hh0,
         const float* __restrict__ w_ih1, const float* __restrict__ w_hh1,
         const float* __restrict__ b_ih1, const float* __restrict__ b_hh1,
         const float* __restrict__ fc_w, const float* __restrict__ fc_b,
         float* __restrict__ out)
{
    const int tid  = threadIdx.x;
    const int wv   = tid >> 6;           // 0: layer-0 wave, 1: layer-1 wave
    const int lane = tid & 63;
    const int sl   = lane / H_;          // 0..2 active, 3 = idle lanes
    const int i    = lane - sl * H_;     // h-index 0..19
    const int samp = blockIdx.x * SPW + sl;
    const int sc   = (samp < B_) ? samp : (B_ - 1);
    const int slc  = (sl < SPW) ? sl : SPW;   // idle lanes -> spare row

    __shared__ __align__(16) float h1s[2][SPW + 1][H_];  // handoff, double-buffered
    __shared__ __align__(16) float h2s[SPW + 1][H_];     // wave1-internal exchange

    if (wv == 0) {
        // ---------------- layer-0 producer wave ----------------
        float wi0[DIN];
        {
            const float2* p = reinterpret_cast<const float2*>(w_ih0 + i * DIN);
            #pragma unroll
            for (int k = 0; k < DIN / 2; ++k) { float2 v = p[k]; wi0[2*k] = v.x; wi0[2*k+1] = v.y; }
        }
        float wh0[H_];
        {
            const float4* p = reinterpret_cast<const float4*>(w_hh0 + i * H_);
            #pragma unroll
            for (int k = 0; k < H_ / 4; ++k) {
                float4 v = p[k]; wh0[4*k]=v.x; wh0[4*k+1]=v.y; wh0[4*k+2]=v.z; wh0[4*k+3]=v.w;
            }
        }
        const float bias0 = b_ih0[i] + b_hh0[i];

        float h1[H_];
        #pragma unroll
        for (int j = 0; j < H_; ++j) h1[j] = 0.0f;

        const float4* xb = reinterpret_cast<const float4*>(x + (size_t)sc * (T_ * DIN));
        float xf[4 * XV];
        #pragma unroll
        for (int k = 0; k < XV; ++k) {
            float4 v = xb[k];
            xf[4*k]=v.x; xf[4*k+1]=v.y; xf[4*k+2]=v.z; xf[4*k+3]=v.w;
        }

        #pragma unroll 1
        for (int t0 = 0; t0 < T_; t0 += CH) {
            // xp burst for this chunk (consumes xf)
            float xp[CH];
            #pragma unroll
            for (int m = 0; m < CH; ++m) {
                float s0 = bias0, s1 = 0.0f;
                #pragma unroll
                for (int d = 0; d < DIN; d += 2) {
                    s0 = fmaf(xf[m*DIN + d],     wi0[d],     s0);
                    s1 = fmaf(xf[m*DIN + d + 1], wi0[d + 1], s1);
                }
                xp[m] = s0 + s1;
            }
            // prefetch next chunk (vmcnt never drained by BAR -> ~4-tick distance)
            {
                const int t0n  = (t0 + CH < T_) ? (t0 + CH) : 0;
                const int base = t0n * DIN / 4;
                #pragma unroll
                for (int k = 0; k < XV; ++k) {
                    float4 v = xb[base + k];
                    xf[4*k]=v.x; xf[4*k+1]=v.y; xf[4*k+2]=v.z; xf[4*k+3]=v.w;
                }
            }
            #pragma unroll
            for (int m = 0; m < CH; ++m) {
                const int p = m & 1;          // t0 % 4 == 0 -> parity is static
                float a0 = xp[m], a1 = 0.f, a2 = 0.f, a3 = 0.f;
                #pragma unroll
                for (int j = 0; j < H_; j += 4) {
                    a0 = fmaf(h1[j+0], wh0[j+0], a0);
                    a1 = fmaf(h1[j+1], wh0[j+1], a1);
                    a2 = fmaf(h1[j+2], wh0[j+2], a2);
                    a3 = fmaf(h1[j+3], wh0[j+3], a3);
                }
                float h1n = fast_tanh((a0 + a1) + (a2 + a3));
                CFENCE();
                h1s[p][slc][i] = h1n;
                LGKM0();                       // write retired -> visible after barrier
                #pragma unroll
                for (int k = 0; k < H_ / 4; ++k) {   // self-readback; retires next tick
                    float4 v = reinterpret_cast<const float4*>(&h1s[p][slc][0])[k];
                    h1[4*k]=v.x; h1[4*k+1]=v.y; h1[4*k+2]=v.z; h1[4*k+3]=v.w;
                }
                CFENCE();
                BAR();
            }
        }
        BAR();   // final tick: wave1 finishes step T-1
    } else {
        // ---------------- layer-1 consumer wave ----------------
        float wi1[H_], wh1[H_];
        {
            const float4* p1 = reinterpret_cast<const float4*>(w_ih1 + i * H_);
            const float4* p2 = reinterpret_cast<const float4*>(w_hh1 + i * H_);
            #pragma unroll
            for (int k = 0; k < H_ / 4; ++k) {
                float4 a = p1[k]; wi1[4*k]=a.x; wi1[4*k+1]=a.y; wi1[4*k+2]=a.z; wi1[4*k+3]=a.w;
                float4 b = p2[k]; wh1[4*k]=b.x; wh1[4*k+1]=b.y; wh1[4*k+2]=b.z; wh1[4*k+3]=b.w;
            }
        }
        const float bias1 = b_ih1[i] + b_hh1[i];
        float h2[H_];
        #pragma unroll
        for (int j = 0; j < H_; ++j) h2[j] = 0.0f;

        BAR();   // tick 0: wave0 produces h1(0)

        #pragma unroll 2
        for (int t = 0; t < T_; ++t) {
            const int p = t & 1;             // slot holding h1(t)
            // start with the handoff-independent h2(t-1).w_hh1 product
            float b0 = bias1, b1 = 0.f, b2 = 0.f, b3 = 0.f;
            #pragma unroll
            for (int j = 0; j < H_; j += 4) {
                b0 = fmaf(h2[j+0], wh1[j+0], b0);
                b1 = fmaf(h2[j+1], wh1[j+1], b1);
                b2 = fmaf(h2[j+2], wh1[j+2], b2);
                b3 = fmaf(h2[j+3], wh1[j+3], b3);
            }
            float h1v[H_];
            #pragma unroll
            for (int k = 0; k < H_ / 4; ++k) {
                float4 v = reinterpret_cast<const float4*>(&h1s[p][slc][0])[k];
                h1v[4*k]=v.x; h1v[4*k+1]=v.y; h1v[4*k+2]=v.z; h1v[4*k+3]=v.w;
            }
            #pragma unroll
            for (int j = 0; j < H_; j += 4) {
                b0 = fmaf(h1v[j+0], wi1[j+0], b0);
                b1 = fmaf(h1v[j+1], wi1[j+1], b1);
                b2 = fmaf(h1v[j+2], wi1[j+2], b2);
                b3 = fmaf(h1v[j+3], wi1[j+3], b3);
            }
            float h2n = fast_tanh((b0 + b1) + (b2 + b3));
            CFENCE();
            h2s[slc][i] = h2n;
            CFENCE();
            #pragma unroll
            for (int k = 0; k < H_ / 4; ++k) {   // wave-synchronous self-exchange
                float4 v = reinterpret_cast<const float4*>(&h2s[slc][0])[k];
                h2[4*k]=v.x; h2[4*k+1]=v.y; h2[4*k+2]=v.z; h2[4*k+3]=v.w;
            }
            CFENCE();
            BAR();
        }

        // ---- FC epilogue: wave1 holds final h2 in registers ----
        if (sl < SPW && samp < B_ && i < DOUT) {
            float acc = fc_b[i];
            #pragma unroll
            for (int j = 0; j < H_; ++j) acc = fmaf(h2[j], fc_w[i * H_ + j], acc);
            out[samp * DOUT + i] = acc;
        }
    }
}

extern "C" void kernel_launch(void* const* d_in, const int* in_sizes, int n_in,
                              void* d_out, int out_size, void* d_ws, size_t ws_size,
                              hipStream_t stream) {
    (void)in_sizes; (void)n_in; (void)d_ws; (void)ws_size; (void)out_size;
    const float* x     = (const float*)d_in[0];
    const float* w_ih0 = (const float*)d_in[1];
    const float* w_hh0 = (const float*)d_in[2];
    const float* b_ih0 = (const float*)d_in[3];
    const float* b_hh0 = (const float*)d_in[4];
    const float* w_ih1 = (const float*)d_in[5];
    const float* w_hh1 = (const float*)d_in[6];
    const float* b_ih1 = (const float*)d_in[7];
    const float* b_hh1 = (const float*)d_in[8];
    const float* fc_w  = (const float*)d_in[9];
    const float* fc_b  = (const float*)d_in[10];
    float* out = (float*)d_out;

    const int grid = (B_ + SPW - 1) / SPW;   // 1366 blocks x 2 waves
    hipLaunchKernelGGL(rnn_pipe, dim3(grid), dim3(128), 0, stream,
                       x, w_ih0, w_hh0, b_ih0, b_hh0,
                       w_ih1, w_hh1, b_ih1, b_hh1, fc_w, fc_b, out);
}

// Round 5
// 165.563 us; speedup vs baseline: 1.1891x; 1.1891x over previous
//
#include <hip/hip_runtime.h>
#include <cstdint>

// Problem constants (from reference)
constexpr int B_   = 4096;
constexpr int T_   = 512;
constexpr int DIN  = 10;
constexpr int H_   = 20;
constexpr int DOUT = 2;

constexpr int SPW = 3;            // samples per wave (3 x 20 = 60 active lanes)
constexpr int CH  = 2;            // timesteps per x-chunk (2*10 floats = 5 float4)
constexpr int XV  = CH * DIN / 4; // float4 prefetch regs per chunk

// Compiler-only memory fence: pins LDS op ordering for wave-synchronous
// exchange (single-wave workgroup; same-wave DS ops execute in order in HW).
#define CFENCE() asm volatile("" ::: "memory")
// Register pin: forces the value to materialize in a VGPR here and makes the
// producing load non-rematerializable (asm results can't be re-derived), so
// loop-invariant weights stay resident across the t-loop instead of being
// re-loaded from global memory every iteration.
#define PIN(v)   asm volatile("" : "+v"(v))

__device__ __forceinline__ float fast_tanh(float v) {
    // tanh(v) = 1 - 2/(exp2(2*log2e*v)+1): 5 VALU ops, exact saturation
    float e = __builtin_amdgcn_exp2f(v * 2.885390082f);
    float r = __builtin_amdgcn_rcpf(e + 1.0f);
    return fmaf(-2.0f, r, 1.0f);
}

extern "C" __global__ void __launch_bounds__(64, 1)
rnn_fused(const float* __restrict__ x,
          const float* __restrict__ w_ih0, const float* __restrict__ w_hh0,
          const float* __restrict__ b_ih0, const float* __restrict__ b_hh0,
          const float* __restrict__ w_ih1, const float* __restrict__ w_hh1,
          const float* __restrict__ b_ih1, const float* __restrict__ b_hh1,
          const float* __restrict__ fc_w, const float* __restrict__ fc_b,
          float* __restrict__ out)
{
    const int lane = threadIdx.x;
    const int sl   = lane / H_;          // 0..2 active, 3 = idle lanes 60..63
    const int i    = lane - sl * H_;     // h-index 0..19
    const int samp = blockIdx.x * SPW + sl;
    const int sc   = (samp < B_) ? samp : (B_ - 1);   // clamped for safe loads
    const int slc  = (sl < SPW) ? sl : SPW;           // idle lanes -> spare row

    __shared__ __align__(16) float h1s[SPW + 1][H_];
    __shared__ __align__(16) float h2s[SPW + 1][H_];

    // ---- per-lane weight rows in registers (loop-invariant) ----
    float wi0[DIN];
    {
        const float2* p = reinterpret_cast<const float2*>(w_ih0 + i * DIN);
        #pragma unroll
        for (int k = 0; k < DIN / 2; ++k) {
            float2 v = p[k];
            wi0[2 * k] = v.x; wi0[2 * k + 1] = v.y;
        }
    }
    float wh0[H_], wi1[H_], wh1[H_];
    {
        const float4* p0 = reinterpret_cast<const float4*>(w_hh0 + i * H_);
        const float4* p1 = reinterpret_cast<const float4*>(w_ih1 + i * H_);
        const float4* p2 = reinterpret_cast<const float4*>(w_hh1 + i * H_);
        #pragma unroll
        for (int k = 0; k < H_ / 4; ++k) {
            float4 a = p0[k]; wh0[4*k]=a.x; wh0[4*k+1]=a.y; wh0[4*k+2]=a.z; wh0[4*k+3]=a.w;
            float4 b = p1[k]; wi1[4*k]=b.x; wi1[4*k+1]=b.y; wi1[4*k+2]=b.z; wi1[4*k+3]=b.w;
            float4 c = p2[k]; wh1[4*k]=c.x; wh1[4*k+1]=c.y; wh1[4*k+2]=c.z; wh1[4*k+3]=c.w;
        }
    }
    float bias0 = b_ih0[i] + b_hh0[i];
    float bias1 = b_ih1[i] + b_hh1[i];

    // ---- pin all loop-invariant values into VGPRs (defeats rematerialization) ----
    #pragma unroll
    for (int k = 0; k < DIN; ++k) PIN(wi0[k]);
    #pragma unroll
    for (int k = 0; k < H_; ++k)  PIN(wh0[k]);
    #pragma unroll
    for (int k = 0; k < H_; ++k)  PIN(wi1[k]);
    #pragma unroll
    for (int k = 0; k < H_; ++k)  PIN(wh1[k]);
    PIN(bias0); PIN(bias1);

    // ---- h-state natively as float4 (read straight from LDS, no repack) ----
    float4 h1q[H_ / 4], h2q[H_ / 4];
    #pragma unroll
    for (int k = 0; k < H_ / 4; ++k) {
        h1q[k] = make_float4(0.f, 0.f, 0.f, 0.f);
        h2q[k] = make_float4(0.f, 0.f, 0.f, 0.f);
    }

    const float4* xb = reinterpret_cast<const float4*>(x + (size_t)sc * (T_ * DIN));

    // ---- prologue: prefetch chunk 0 ----
    float4 xv[XV];
    #pragma unroll
    for (int k = 0; k < XV; ++k) xv[k] = xb[k];

    for (int t0 = 0; t0 < T_; t0 += CH) {
        // ---- consume prefetched xv -> xp ----
        float xp[CH];
        #pragma unroll
        for (int m = 0; m < CH; ++m) xp[m] = bias0;
        #pragma unroll
        for (int k = 0; k < XV; ++k) {
            int idx = 4 * k;
            xp[(idx+0)/DIN] = fmaf(xv[k].x, wi0[(idx+0)%DIN], xp[(idx+0)/DIN]);
            xp[(idx+1)/DIN] = fmaf(xv[k].y, wi0[(idx+1)%DIN], xp[(idx+1)/DIN]);
            xp[(idx+2)/DIN] = fmaf(xv[k].z, wi0[(idx+2)%DIN], xp[(idx+2)/DIN]);
            xp[(idx+3)/DIN] = fmaf(xv[k].w, wi0[(idx+3)%DIN], xp[(idx+3)/DIN]);
        }

        // ---- issue next chunk's loads; wait lands ~2 steps (~500cy) later ----
        {
            const int t0n = (t0 + CH < T_) ? (t0 + CH) : 0;  // clamp, branchless
            #pragma unroll
            for (int k = 0; k < XV; ++k) xv[k] = xb[(t0n * DIN) / 4 + k];
        }

        #pragma unroll
        for (int m = 0; m < CH; ++m) {
            // ---- layer 0: a = xp + h1(t-1) . w_hh0[i,:] ----
            float a0 = xp[m], a1 = 0.f, a2 = 0.f, a3 = 0.f;
            #pragma unroll
            for (int k = 0; k < H_ / 4; ++k) {
                a0 = fmaf(h1q[k].x, wh0[4*k+0], a0);
                a1 = fmaf(h1q[k].y, wh0[4*k+1], a1);
                a2 = fmaf(h1q[k].z, wh0[4*k+2], a2);
                a3 = fmaf(h1q[k].w, wh0[4*k+3], a3);
            }
            float h1n = fast_tanh((a0 + a1) + (a2 + a3));

            // ---- h1 exchange (wave-synchronous, no barrier) ----
            CFENCE();
            h1s[slc][i] = h1n;
            CFENCE();

            // overlap the h1s round-trip with the h2(t-1).w_hh1 product
            float b0 = bias1, b1 = 0.f, b2 = 0.f, b3 = 0.f;
            #pragma unroll
            for (int k = 0; k < H_ / 4; ++k) {
                b0 = fmaf(h2q[k].x, wh1[4*k+0], b0);
                b1 = fmaf(h2q[k].y, wh1[4*k+1], b1);
                b2 = fmaf(h2q[k].z, wh1[4*k+2], b2);
                b3 = fmaf(h2q[k].w, wh1[4*k+3], b3);
            }

            #pragma unroll
            for (int k = 0; k < H_ / 4; ++k)
                h1q[k] = reinterpret_cast<const float4*>(&h1s[slc][0])[k];
            CFENCE();

            // ---- layer 1: b += h1(t) . w_ih1[i,:] ----
            #pragma unroll
            for (int k = 0; k < H_ / 4; ++k) {
                b0 = fmaf(h1q[k].x, wi1[4*k+0], b0);
                b1 = fmaf(h1q[k].y, wi1[4*k+1], b1);
                b2 = fmaf(h1q[k].z, wi1[4*k+2], b2);
                b3 = fmaf(h1q[k].w, wi1[4*k+3], b3);
            }
            float h2n = fast_tanh((b0 + b1) + (b2 + b3));

            // ---- h2 exchange; read-back latency hides under next layer-0 ----
            CFENCE();
            h2s[slc][i] = h2n;
            CFENCE();
            #pragma unroll
            for (int k = 0; k < H_ / 4; ++k)
                h2q[k] = reinterpret_cast<const float4*>(&h2s[slc][0])[k];
            CFENCE();
        }
    }

    // ---- FC epilogue: lanes i<2 hold full h2; out[samp][i] ----
    if (sl < SPW && samp < B_ && i < DOUT) {
        float hf[H_];
        #pragma unroll
        for (int k = 0; k < H_ / 4; ++k) {
            hf[4*k+0] = h2q[k].x; hf[4*k+1] = h2q[k].y;
            hf[4*k+2] = h2q[k].z; hf[4*k+3] = h2q[k].w;
        }
        float acc = fc_b[i];
        #pragma unroll
        for (int j = 0; j < H_; ++j) acc = fmaf(hf[j], fc_w[i * H_ + j], acc);
        out[samp * DOUT + i] = acc;
    }
}

extern "C" void kernel_launch(void* const* d_in, const int* in_sizes, int n_in,
                              void* d_out, int out_size, void* d_ws, size_t ws_size,
                              hipStream_t stream) {
    (void)in_sizes; (void)n_in; (void)d_ws; (void)ws_size; (void)out_size;
    const float* x     = (const float*)d_in[0];
    const float* w_ih0 = (const float*)d_in[1];
    const float* w_hh0 = (const float*)d_in[2];
    const float* b_ih0 = (const float*)d_in[3];
    const float* b_hh0 = (const float*)d_in[4];
    const float* w_ih1 = (const float*)d_in[5];
    const float* w_hh1 = (const float*)d_in[6];
    const float* b_ih1 = (const float*)d_in[7];
    const float* b_hh1 = (const float*)d_in[8];
    const float* fc_w  = (const float*)d_in[9];
    const float* fc_b  = (const float*)d_in[10];
    float* out = (float*)d_out;

    const int grid = (B_ + SPW - 1) / SPW;   // 1366 single-wave blocks
    hipLaunchKernelGGL(rnn_fused, dim3(grid), dim3(64), 0, stream,
                       x, w_ih0, w_hh0, b_ih0, b_hh0,
                       w_ih1, w_hh1, b_ih1, b_hh1, fc_w, fc_b, out);
}

// Round 6
// 154.292 us; speedup vs baseline: 1.2759x; 1.0731x over previous
//
#include <hip/hip_runtime.h>
#include <cstdint>

// Problem constants (from reference)
constexpr int B_   = 4096;
constexpr int T_   = 512;
constexpr int DIN  = 10;
constexpr int H_   = 20;
constexpr int DOUT = 2;

constexpr int SPW = 3;            // samples per wave (3 x 20 = 60 active lanes)
constexpr int CH  = 4;            // timesteps per x-chunk (4*10 floats = 10 float4)
constexpr int XV  = CH * DIN / 4; // float4 prefetch regs per chunk

// Compiler-only memory fence: pins LDS op ordering for wave-synchronous
// exchange (single-wave workgroup; same-wave DS ops execute in order in HW).
#define CFENCE() asm volatile("" ::: "memory")

__device__ __forceinline__ float fast_tanh(float v) {
    // tanh(v) = 1 - 2/(exp2(2*log2e*v)+1): exact saturation at +/-inf
    float e = __builtin_amdgcn_exp2f(v * 2.885390082f);
    float r = __builtin_amdgcn_rcpf(e + 1.0f);
    return fmaf(-2.0f, r, 1.0f);
}

// Skewed 2-layer RNN: per iteration tau we compute
//   h1(tau)   = tanh(xp[tau] + wh0 . h1(tau-1))          [L0]
//   h2(tau-1) = tanh(bias1 + wi1 . h1(tau-1) + wh1 . h2(tau-2))   [L1, skewed]
// Both consume only register state -> 60 independent FMAs + 2 independent
// tanhs per step, then ONE batched LDS exchange (2 writes + 10 b128 reads)
// instead of two serialized round-trips.
extern "C" __global__ void __launch_bounds__(64, 1)
rnn_skew(const float* __restrict__ x,
         const float* __restrict__ w_ih0, const float* __restrict__ w_hh0,
         const float* __restrict__ b_ih0, const float* __restrict__ b_hh0,
         const float* __restrict__ w_ih1, const float* __restrict__ w_hh1,
         const float* __restrict__ b_ih1, const float* __restrict__ b_hh1,
         const float* __restrict__ fc_w, const float* __restrict__ fc_b,
         float* __restrict__ out)
{
    const int lane = threadIdx.x;
    const int sl   = lane / H_;          // 0..2 active, 3 = idle lanes 60..63
    const int i    = lane - sl * H_;     // h-index 0..19
    const int samp = blockIdx.x * SPW + sl;
    const int sc   = (samp < B_) ? samp : (B_ - 1);   // clamped for safe loads
    const int slc  = (sl < SPW) ? sl : SPW;           // idle lanes -> spare row

    __shared__ __align__(16) float h1s[SPW + 1][H_];
    __shared__ __align__(16) float h2s[SPW + 1][H_];

    // ---- per-lane weight rows in registers (loop-invariant) ----
    float wi0[DIN];
    {
        const float2* p = reinterpret_cast<const float2*>(w_ih0 + i * DIN);
        #pragma unroll
        for (int k = 0; k < DIN / 2; ++k) {
            float2 v = p[k];
            wi0[2 * k] = v.x; wi0[2 * k + 1] = v.y;
        }
    }
    float wh0[H_], wi1[H_], wh1[H_];
    {
        const float4* p0 = reinterpret_cast<const float4*>(w_hh0 + i * H_);
        const float4* p1 = reinterpret_cast<const float4*>(w_ih1 + i * H_);
        const float4* p2 = reinterpret_cast<const float4*>(w_hh1 + i * H_);
        #pragma unroll
        for (int k = 0; k < H_ / 4; ++k) {
            float4 a = p0[k]; wh0[4*k]=a.x; wh0[4*k+1]=a.y; wh0[4*k+2]=a.z; wh0[4*k+3]=a.w;
            float4 b = p1[k]; wi1[4*k]=b.x; wi1[4*k+1]=b.y; wi1[4*k+2]=b.z; wi1[4*k+3]=b.w;
            float4 c = p2[k]; wh1[4*k]=c.x; wh1[4*k+1]=c.y; wh1[4*k+2]=c.z; wh1[4*k+3]=c.w;
        }
    }
    const float bias0 = b_ih0[i] + b_hh0[i];
    const float bias1 = b_ih1[i] + b_hh1[i];

    // ---- register state: h1q = h1(tau-1), h2q = h2(tau-2) ----
    float4 h1q[H_ / 4], h2q[H_ / 4];
    #pragma unroll
    for (int k = 0; k < H_ / 4; ++k) {
        h1q[k] = make_float4(0.f, 0.f, 0.f, 0.f);
        h2q[k] = make_float4(0.f, 0.f, 0.f, 0.f);
    }

    const float4* xb = reinterpret_cast<const float4*>(x + (size_t)sc * (T_ * DIN));

    // ---- prologue: prefetch chunk 0 ----
    float4 xv[XV];
    #pragma unroll
    for (int k = 0; k < XV; ++k) xv[k] = xb[k];

    // one full skewed step (computes h1(tau) and h2(tau-1), one LDS exchange)
    auto full_step = [&](float xpm) {
        float a0 = xpm, a1 = 0.f, a2 = 0.f, a3 = 0.f;          // L0
        float b0 = bias1, b1 = 0.f, b2 = 0.f, b3 = 0.f;        // L1 (skewed)
        #pragma unroll
        for (int k = 0; k < H_ / 4; ++k) {
            a0 = fmaf(h1q[k].x, wh0[4*k+0], a0);
            a1 = fmaf(h1q[k].y, wh0[4*k+1], a1);
            a2 = fmaf(h1q[k].z, wh0[4*k+2], a2);
            a3 = fmaf(h1q[k].w, wh0[4*k+3], a3);
            b0 = fmaf(h1q[k].x, wi1[4*k+0], b0);
            b1 = fmaf(h1q[k].y, wi1[4*k+1], b1);
            b2 = fmaf(h1q[k].z, wi1[4*k+2], b2);
            b3 = fmaf(h1q[k].w, wi1[4*k+3], b3);
        }
        #pragma unroll
        for (int k = 0; k < H_ / 4; ++k) {
            b0 = fmaf(h2q[k].x, wh1[4*k+0], b0);
            b1 = fmaf(h2q[k].y, wh1[4*k+1], b1);
            b2 = fmaf(h2q[k].z, wh1[4*k+2], b2);
            b3 = fmaf(h2q[k].w, wh1[4*k+3], b3);
        }
        float h1n = fast_tanh((a0 + a1) + (a2 + a3));
        float h2n = fast_tanh((b0 + b1) + (b2 + b3));
        // ---- single batched exchange (wave-synchronous, no barrier) ----
        CFENCE();
        h1s[slc][i] = h1n;
        h2s[slc][i] = h2n;
        CFENCE();
        #pragma unroll
        for (int k = 0; k < H_ / 4; ++k)
            h1q[k] = reinterpret_cast<const float4*>(&h1s[slc][0])[k];
        #pragma unroll
        for (int k = 0; k < H_ / 4; ++k)
            h2q[k] = reinterpret_cast<const float4*>(&h2s[slc][0])[k];
        CFENCE();
    };

    // consume xv -> xp for a chunk
    auto consume_xp = [&](float* xp) {
        #pragma unroll
        for (int m = 0; m < CH; ++m) xp[m] = bias0;
        #pragma unroll
        for (int k = 0; k < XV; ++k) {
            int idx = 4 * k;
            xp[(idx+0)/DIN] = fmaf(xv[k].x, wi0[(idx+0)%DIN], xp[(idx+0)/DIN]);
            xp[(idx+1)/DIN] = fmaf(xv[k].y, wi0[(idx+1)%DIN], xp[(idx+1)/DIN]);
            xp[(idx+2)/DIN] = fmaf(xv[k].z, wi0[(idx+2)%DIN], xp[(idx+2)/DIN]);
            xp[(idx+3)/DIN] = fmaf(xv[k].w, wi0[(idx+3)%DIN], xp[(idx+3)/DIN]);
        }
    };

    // ---- chunk 0 (tau = 0..CH-1), tau=0 peeled: h1(0)=tanh(xp[0]), h2 untouched ----
    {
        float xp[CH];
        consume_xp(xp);
        #pragma unroll
        for (int k = 0; k < XV; ++k) xv[k] = xb[(CH * DIN) / 4 + k];  // prefetch chunk 1

        float h1n = fast_tanh(xp[0]);
        CFENCE();
        h1s[slc][i] = h1n;
        CFENCE();
        #pragma unroll
        for (int k = 0; k < H_ / 4; ++k)
            h1q[k] = reinterpret_cast<const float4*>(&h1s[slc][0])[k];
        CFENCE();

        #pragma unroll
        for (int m = 1; m < CH; ++m) full_step(xp[m]);
    }

    // ---- main loop: chunks t0 = CH .. T-CH ----
    for (int t0 = CH; t0 < T_; t0 += CH) {
        float xp[CH];
        consume_xp(xp);
        {
            const int t0n = (t0 + CH < T_) ? (t0 + CH) : 0;  // clamp, branchless
            #pragma unroll
            for (int k = 0; k < XV; ++k) xv[k] = xb[(t0n * DIN) / 4 + k];
        }
        #pragma unroll
        for (int m = 0; m < CH; ++m) full_step(xp[m]);
    }

    // ---- epilogue: h2(T-1) from h1(T-1) (=h1q) and h2(T-2) (=h2q) ----
    {
        float b0 = bias1, b1 = 0.f, b2 = 0.f, b3 = 0.f;
        #pragma unroll
        for (int k = 0; k < H_ / 4; ++k) {
            b0 = fmaf(h1q[k].x, wi1[4*k+0], b0);
            b1 = fmaf(h1q[k].y, wi1[4*k+1], b1);
            b2 = fmaf(h1q[k].z, wi1[4*k+2], b2);
            b3 = fmaf(h1q[k].w, wi1[4*k+3], b3);
        }
        #pragma unroll
        for (int k = 0; k < H_ / 4; ++k) {
            b0 = fmaf(h2q[k].x, wh1[4*k+0], b0);
            b1 = fmaf(h2q[k].y, wh1[4*k+1], b1);
            b2 = fmaf(h2q[k].z, wh1[4*k+2], b2);
            b3 = fmaf(h2q[k].w, wh1[4*k+3], b3);
        }
        float h2n = fast_tanh((b0 + b1) + (b2 + b3));
        CFENCE();
        h2s[slc][i] = h2n;
        CFENCE();
        #pragma unroll
        for (int k = 0; k < H_ / 4; ++k)
            h2q[k] = reinterpret_cast<const float4*>(&h2s[slc][0])[k];
        CFENCE();
    }

    // ---- FC: lanes i<2 hold full h2(T-1); out[samp][i] ----
    if (sl < SPW && samp < B_ && i < DOUT) {
        float hf[H_];
        #pragma unroll
        for (int k = 0; k < H_ / 4; ++k) {
            hf[4*k+0] = h2q[k].x; hf[4*k+1] = h2q[k].y;
            hf[4*k+2] = h2q[k].z; hf[4*k+3] = h2q[k].w;
        }
        float acc = fc_b[i];
        #pragma unroll
        for (int j = 0; j < H_; ++j) acc = fmaf(hf[j], fc_w[i * H_ + j], acc);
        out[samp * DOUT + i] = acc;
    }
}

extern "C" void kernel_launch(void* const* d_in, const int* in_sizes, int n_in,
                              void* d_out, int out_size, void* d_ws, size_t ws_size,
                              hipStream_t stream) {
    (void)in_sizes; (void)n_in; (void)d_ws; (void)ws_size; (void)out_size;
    const float* x     = (const float*)d_in[0];
    const float* w_ih0 = (const float*)d_in[1];
    const float* w_hh0 = (const float*)d_in[2];
    const float* b_ih0 = (const float*)d_in[3];
    const float* b_hh0 = (const float*)d_in[4];
    const float* w_ih1 = (const float*)d_in[5];
    const float* w_hh1 = (const float*)d_in[6];
    const float* b_ih1 = (const float*)d_in[7];
    const float* b_hh1 = (const float*)d_in[8];
    const float* fc_w  = (const float*)d_in[9];
    const float* fc_b  = (const float*)d_in[10];
    float* out = (float*)d_out;

    const int grid = (B_ + SPW - 1) / SPW;   // 1366 single-wave blocks
    hipLaunchKernelGGL(rnn_skew, dim3(grid), dim3(64), 0, stream,
                       x, w_ih0, w_hh0, b_ih0, b_hh0,
                       w_ih1, w_hh1, b_ih1, b_hh1, fc_w, fc_b, out);
}